// Round 9
// baseline (3994.098 us; speedup 1.0000x reference)
//
#include <hip/hip_runtime.h>

#define TSEQ 2048
#define NB   32
#define HIDN 256
#define NG   1024   // 4*HID

typedef _Float16 half_t;
typedef _Float16 half2_t __attribute__((ext_vector_type(2)));

__device__ __forceinline__ float fdot2f16(unsigned int a, unsigned int b, float c) {
#if __has_builtin(__builtin_amdgcn_fdot2)
    return __builtin_amdgcn_fdot2(__builtin_bit_cast(half2_t, a),
                                  __builtin_bit_cast(half2_t, b), c, false);
#else
    half2_t x = __builtin_bit_cast(half2_t, a);
    half2_t y = __builtin_bit_cast(half2_t, b);
    return c + (float)x[0] * (float)y[0] + (float)x[1] * (float)y[1];
#endif
}

__device__ __forceinline__ unsigned int packh2(float lo, float hi) {
    half_t l = (half_t)lo, h = (half_t)hi;
    return (unsigned int)__builtin_bit_cast(unsigned short, l) |
           ((unsigned int)__builtin_bit_cast(unsigned short, h) << 16);
}

__device__ __forceinline__ float fast_exp2(float x) {
#if __has_builtin(__builtin_amdgcn_exp2f)
    return __builtin_amdgcn_exp2f(x);
#else
    return exp2f(x);
#endif
}
__device__ __forceinline__ float fast_rcp(float x) {
#if __has_builtin(__builtin_amdgcn_rcpf)
    return __builtin_amdgcn_rcpf(x);
#else
    return 1.0f / x;
#endif
}

__device__ __forceinline__ float tanh_fast(float x) {
    float e = fast_exp2(x * 2.885390082f);
    return 1.0f - 2.0f * fast_rcp(e + 1.0f);
}

// ---------------------------------------------------------------------------
// K1: pack weights (layouts unchanged from round 5).
//  Wh -> Whp[chunk*1024 + t], chunk = g*8+p, t: kq = t&3, cg = t>>2,
//    col = g*256+cg, k0 = kq*64 + p*8; uint4 d: pack(Wh[k0+2d], Wh[k0+2d+1]).
//  Wi -> Wip (xproj_gemm layout, unchanged).
// ---------------------------------------------------------------------------
__global__ void pack_w(const float* __restrict__ Wi, const float* __restrict__ Wh,
                       uint4* __restrict__ Whp, uint4* __restrict__ Wip) {
    int idx = blockIdx.x * 256 + threadIdx.x;   // 0..65535
    if (idx < 32768) {
        int chunk = idx >> 10, t = idx & 1023;
        int g = chunk >> 3, p = chunk & 7;
        int kq = t & 3, cg = t >> 2;
        int col = g * 256 + cg;
        int k0 = kq * 64 + p * 8;
        Whp[idx] = make_uint4(
            packh2(Wh[(k0 + 0) * NG + col], Wh[(k0 + 1) * NG + col]),
            packh2(Wh[(k0 + 2) * NG + col], Wh[(k0 + 3) * NG + col]),
            packh2(Wh[(k0 + 4) * NG + col], Wh[(k0 + 5) * NG + col]),
            packh2(Wh[(k0 + 6) * NG + col], Wh[(k0 + 7) * NG + col]));
    } else {
        int li = idx & 32767;
        int m4 = li >> 10, tt = li & 1023;
        int col = (tt & 3) * 256 + (tt >> 2);
        int k0 = m4 * 8;
        Wip[li] = make_uint4(
            packh2(Wi[(k0 + 0) * NG + col], Wi[(k0 + 1) * NG + col]),
            packh2(Wi[(k0 + 2) * NG + col], Wi[(k0 + 3) * NG + col]),
            packh2(Wi[(k0 + 4) * NG + col], Wi[(k0 + 5) * NG + col]),
            packh2(Wi[(k0 + 6) * NG + col], Wi[(k0 + 7) * NG + col]));
    }
}

// ---------------------------------------------------------------------------
// K2: x_proj GEMM (unchanged): X [65536][256] fp32 @ Wi -> XP ushort4,
// gate-interleaved f16: half index row*1024 + j*4 + g.
// ---------------------------------------------------------------------------
__global__ __launch_bounds__(1024) void xproj_gemm(
    const float* __restrict__ X, const uint4* __restrict__ Wip,
    ushort4* __restrict__ XP)
{
    __shared__ uint4 atile[32][32];
    const int tid = threadIdx.x;
    const long row0 = (long)blockIdx.x * 32;

    {
        int r = tid >> 5, kc = tid & 31;
        const float4* src = (const float4*)(X + (row0 + r) * 256 + kc * 8);
        float4 f0 = src[0], f1 = src[1];
        atile[r][kc] = make_uint4(packh2(f0.x, f0.y), packh2(f0.z, f0.w),
                                  packh2(f1.x, f1.y), packh2(f1.z, f1.w));
    }
    __syncthreads();

    const int j = tid & 255, rq = tid >> 8;
    float acc[8][4];
#pragma unroll
    for (int r = 0; r < 8; ++r)
#pragma unroll
        for (int g = 0; g < 4; ++g) acc[r][g] = 0.f;

    unsigned off = (unsigned)(j * 4);
#pragma unroll 2
    for (int m4 = 0; m4 < 32; ++m4) {
        uint4 w0 = Wip[off + 0];
        uint4 w1 = Wip[off + 1];
        uint4 w2 = Wip[off + 2];
        uint4 w3 = Wip[off + 3];
#pragma unroll
        for (int rr = 0; rr < 8; ++rr) {
            uint4 av = atile[rq * 8 + rr][m4];
            acc[rr][0] = fdot2f16(w0.x, av.x, acc[rr][0]);
            acc[rr][0] = fdot2f16(w0.y, av.y, acc[rr][0]);
            acc[rr][0] = fdot2f16(w0.z, av.z, acc[rr][0]);
            acc[rr][0] = fdot2f16(w0.w, av.w, acc[rr][0]);
            acc[rr][1] = fdot2f16(w1.x, av.x, acc[rr][1]);
            acc[rr][1] = fdot2f16(w1.y, av.y, acc[rr][1]);
            acc[rr][1] = fdot2f16(w1.z, av.z, acc[rr][1]);
            acc[rr][1] = fdot2f16(w1.w, av.w, acc[rr][1]);
            acc[rr][2] = fdot2f16(w2.x, av.x, acc[rr][2]);
            acc[rr][2] = fdot2f16(w2.y, av.y, acc[rr][2]);
            acc[rr][2] = fdot2f16(w2.z, av.z, acc[rr][2]);
            acc[rr][2] = fdot2f16(w2.w, av.w, acc[rr][2]);
            acc[rr][3] = fdot2f16(w3.x, av.x, acc[rr][3]);
            acc[rr][3] = fdot2f16(w3.y, av.y, acc[rr][3]);
            acc[rr][3] = fdot2f16(w3.z, av.z, acc[rr][3]);
            acc[rr][3] = fdot2f16(w3.w, av.w, acc[rr][3]);
        }
        off += 1024;
    }

#pragma unroll
    for (int rr = 0; rr < 8; ++rr) {
        long row = row0 + rq * 8 + rr;
        XP[row * 256 + j] = make_ushort4(
            __builtin_bit_cast(unsigned short, (half_t)acc[rr][0]),
            __builtin_bit_cast(unsigned short, (half_t)acc[rr][1]),
            __builtin_bit_cast(unsigned short, (half_t)acc[rr][2]),
            __builtin_bit_cast(unsigned short, (half_t)acc[rr][3]));
    }
}

// ---------------------------------------------------------------------------
// K3: persistent recurrence, weights on-CU.
// __launch_bounds__(1024, 4): 4 waves/EU min -> 128-VGPR budget, so the
// weight registers actually materialize (round-5 counter showed VGPR_Count=64:
// default heuristic targeted 8 waves/EU and rematerialized all 23 chunks from
// L2 every step -> that WAS the bottleneck).
// Weight split: chunks 0..21 in VGPRs (88 regs), 22..30 in LDS (144 KB),
// chunk 31 read from global in-loop (L2-resident pressure valve).
// hpair padded: quarter kq at dword kq*36 (36 = 4 mod 32) so the 4 kq
// addresses hit disjoint banks (round-5: 3.35e7 conflicts from all-kq-same-bank).
// ---------------------------------------------------------------------------
__global__ __launch_bounds__(1024, 4) void lstm_rec(
    const uint4* __restrict__ Whp, const unsigned short* __restrict__ XPh,
    const float* __restrict__ bias, const float* __restrict__ h0,
    const float* __restrict__ c0, float* __restrict__ out)
{
    __shared__ __align__(16) uint4 wlds[9][1024];          // 144 KB
    __shared__ __align__(16) unsigned int hpair[2][144];   // 4 quarters x 36 dwords

    const int tid = threadIdx.x;
    const int b   = blockIdx.x;
    const int kq  = tid & 3;
    const int cg  = tid >> 2;

    // chunks 0..21 -> registers (static indices, full unroll)
    uint4 wr[22];
#pragma unroll
    for (int r = 0; r < 22; ++r) wr[r] = Whp[r * 1024 + tid];
    // chunks 22..30 -> LDS
#pragma unroll
    for (int c = 0; c < 9; ++c) wlds[c][tid] = Whp[(22 + c) * 1024 + tid];

    const float bc = bias[kq * 256 + cg];
    float c_state  = c0[b * HIDN + cg];     // replicated across the quad
    if (tid < 256) {
        // h value j lives at half index (j>>6)*72 + (j&63) (padded quarters)
        ((unsigned short*)hpair[0])[((tid >> 6) * 72) + (tid & 63)] =
            __builtin_bit_cast(unsigned short, (half_t)h0[b * HIDN + tid]);
    }
    const unsigned short* xp = XPh + (long)b * TSEQ * NG + tid;
    const uint4* wtail = Whp + 31 * 1024 + tid;   // chunk 31, in-loop read
    float* ys = out + 2 * NB * HIDN + (long)b * TSEQ * HIDN;
    __syncthreads();

    int buf = 0;
    for (int step = 0; step < TSEQ; ++step) {
        float xpf = (float)__builtin_bit_cast(half_t, xp[(long)step * NG]);
        uint4 wst = *wtail;   // compiler may hoist (4 regs) or remat (L2 hit)

        const unsigned int* hbase = hpair[buf] + kq * 36;
        float p0 = 0.f, p1 = 0.f, p2 = 0.f, p3 = 0.f;
#pragma unroll
        for (int p = 0; p < 8; ++p) {
            uint4 hv = *(const uint4*)(hbase + p * 4);
            uint4 w0 = wr[p];                                   // gate0: 0..7
            uint4 w1 = wr[8 + p];                               // gate1: 8..15
            uint4 w2 = (p < 6) ? wr[16 + p] : wlds[p - 6][tid]; // gate2: 16..21, 22..23
            uint4 w3 = (p < 7) ? wlds[2 + p][tid] : wst;        // gate3: 24..30, 31
            p0 = fdot2f16(w0.x, hv.x, p0); p0 = fdot2f16(w0.y, hv.y, p0);
            p0 = fdot2f16(w0.z, hv.z, p0); p0 = fdot2f16(w0.w, hv.w, p0);
            p1 = fdot2f16(w1.x, hv.x, p1); p1 = fdot2f16(w1.y, hv.y, p1);
            p1 = fdot2f16(w1.z, hv.z, p1); p1 = fdot2f16(w1.w, hv.w, p1);
            p2 = fdot2f16(w2.x, hv.x, p2); p2 = fdot2f16(w2.y, hv.y, p2);
            p2 = fdot2f16(w2.z, hv.z, p2); p2 = fdot2f16(w2.w, hv.w, p2);
            p3 = fdot2f16(w3.x, hv.x, p3); p3 = fdot2f16(w3.y, hv.y, p3);
            p3 = fdot2f16(w3.z, hv.z, p3); p3 = fdot2f16(w3.w, hv.w, p3);
        }

        // quad transpose-reduce: lane kq ends with full z of gate kq, j=cg
        const int q0 = kq & 1, q1 = kq >> 1;
        float keepA = q0 ? p1 : p0;
        float sendA = q0 ? p0 : p1;
        float keepB = q0 ? p3 : p2;
        float sendB = q0 ? p2 : p3;
        keepA += __shfl_xor(sendA, 1);
        keepB += __shfl_xor(sendB, 1);
        float keep = q1 ? keepB : keepA;
        float send = q1 ? keepA : keepB;
        float z = keep + __shfl_xor(send, 2) + xpf + bc;

        // activation: gate 2 (kq==2) tanh, others sigmoid (shared exp2 path)
        float s  = (kq == 2) ? 2.885390082f : -1.442695041f;
        float e  = fast_exp2(z * s);
        float r  = fast_rcp(1.0f + e);
        float a  = (kq == 2) ? 1.0f - 2.0f * r : r;

        // in-quad all-gather of the 4 gate activations
        float b1 = __shfl_xor(a, 1);
        float b2 = __shfl_xor(a, 2);
        float b3 = __shfl_xor(b1, 2);
        float gi = (kq == 0) ? a : (kq == 1) ? b1 : (kq == 2) ? b2 : b3;
        float gf = (kq == 1) ? a : (kq == 0) ? b1 : (kq == 3) ? b2 : b3;
        float gg = (kq == 2) ? a : (kq == 3) ? b1 : (kq == 0) ? b2 : b3;
        float go = (kq == 3) ? a : (kq == 2) ? b1 : (kq == 1) ? b2 : b3;

        float cn = gf * c_state + gi * gg;
        float hn = go * tanh_fast(cn);
        c_state = cn;

        if (kq == 0) {
            ((unsigned short*)hpair[buf ^ 1])[((cg >> 6) * 72) + (cg & 63)] =
                __builtin_bit_cast(unsigned short, (half_t)hn);
            ys[(long)step * HIDN + cg] = hn;
            if (step == TSEQ - 1) {
                out[b * HIDN + cg] = hn;                  // hT
                out[NB * HIDN + b * HIDN + cg] = cn;      // cT
            }
        }
        __syncthreads();
        buf ^= 1;
    }
}

// ---------------------------------------------------------------------------
extern "C" void kernel_launch(void* const* d_in, const int* in_sizes, int n_in,
                              void* d_out, int out_size, void* d_ws, size_t ws_size,
                              hipStream_t stream) {
    const float* X  = (const float*)d_in[0];   // [32][2048][256]
    const float* Wi = (const float*)d_in[1];   // [256][1024]
    const float* Wh = (const float*)d_in[2];   // [256][1024]
    const float* bv = (const float*)d_in[3];   // [1024]
    const float* h0 = (const float*)d_in[4];   // [32][256]
    const float* c0 = (const float*)d_in[5];   // [32][256]
    float* out = (float*)d_out;

    char* ws = (char*)d_ws;
    uint4* Whp = (uint4*)(ws);                       // 512 KB
    uint4* Wip = (uint4*)(ws + (512 << 10));         // 512 KB
    unsigned short* XPh = (unsigned short*)(ws + (1 << 20));  // 128 MB

    pack_w<<<256, 256, 0, stream>>>(Wi, Wh, Whp, Wip);
    xproj_gemm<<<2048, 1024, 0, stream>>>(X, Wip, (ushort4*)XPh);
    lstm_rec<<<NB, 1024, 0, stream>>>(Whp, XPh, bv, h0, c0, out);
}